// Round 1
// baseline (154.051 us; speedup 1.0000x reference)
//
#include <hip/hip_runtime.h>
#include <math.h>

#define BATCH 16
#define CHN   16
#define IMH   96
#define IMW   320
#define HW    (IMH*IMW)          /* 30720 */
#define NBLK  (HW/256)           /* 120 blocks per batch */
#define NPART 27                 /* 21 (sym H) + 6 (b) */

// ---------------- kernel 0: transpose tgt_feat (B,C,H,W) -> (B,H,W,C) ----------------
__global__ __launch_bounds__(256) void transpose_tgt(const float* __restrict__ in,
                                                     float* __restrict__ out) {
    __shared__ float tile[64][17];
    const int b  = blockIdx.y;
    const int p0 = blockIdx.x * 64;
    const int t  = threadIdx.x;
    const int pi = t & 63, cq = t >> 6;
#pragma unroll
    for (int k = 0; k < 4; ++k) {
        int c = cq * 4 + k;
        tile[pi][c] = in[(size_t)(b * CHN + c) * HW + p0 + pi];
    }
    __syncthreads();
#pragma unroll
    for (int k = 0; k < 4; ++k) {
        int e = t + k * 256;
        int pp = e >> 4, c = e & 15;
        out[(size_t)(b * HW + p0 + pp) * CHN + c] = tile[pp][c];
    }
}

// ---------------- kernel 1: per-point moments + block-partial H/b ----------------
__global__ __launch_bounds__(256) void gn_accum(
    const float* __restrict__ p2,       // (B,2,5,1,H,W)
    const float* __restrict__ P2,       // (B,3,HW)
    const float* __restrict__ calibK,   // (B,3,3)
    const float* __restrict__ weight,   // (B,1,H,W)
    const float* __restrict__ src_feat, // (B,C,H,W)
    const float* __restrict__ src_w,    // (B,1,H,W)
    const float* __restrict__ tgt_w,    // (B,1,H,W)
    const float* __restrict__ tfT,      // (B,H,W,C) transposed tgt_feat
    float* __restrict__ partials)       // (B, NBLK, NPART)
{
    const int b = blockIdx.y;
    const int p = blockIdx.x * 256 + threadIdx.x;

    // ---- scrambled grid coords (faithful to transpose+reshape in reference) ----
    int   off[5];          // corner (y0,x0) base offset into tfT (floats)
    float wxs[5], wys[5];
    int   pix00 = 0;       // pixel offset for tgt_w bilinear (sample 0)
    const unsigned Gbase = ((unsigned)b * HW + (unsigned)p) * 5u;
#pragma unroll
    for (int s = 0; s < 5; ++s) {
        unsigned G    = Gbase + (unsigned)s;
        unsigned sBig = G / (unsigned)(BATCH * HW);
        unsigned r    = G - sBig * (unsigned)(BATCH * HW);
        unsigned bb   = r / (unsigned)HW;
        unsigned q    = r - bb * (unsigned)HW;
        const float* pb = p2 + (size_t)bb * (10 * HW) + (size_t)sBig * HW + q;
        float xp = pb[0];
        float yp = pb[5 * HW];
        // replicate reference normalization/unnormalization arithmetic
        float gx = 2.0f * (xp + 0.5f) / (float)IMW - 1.0f;
        float gy = 2.0f * (yp + 0.5f) / (float)IMH - 1.0f;
        float x  = (gx + 1.0f) * ((float)IMW * 0.5f) - 0.5f;
        float y  = (gy + 1.0f) * ((float)IMH * 0.5f) - 0.5f;
        float x0 = floorf(x), y0 = floorf(y);
        wxs[s] = x - x0;
        wys[s] = y - y0;
        int xi = (int)x0, yi = (int)y0;
        xi = min(max(xi, 0), IMW - 2);
        yi = min(max(yi, 0), IMH - 2);
        off[s] = ((b * IMH + yi) * IMW + xi) * CHN;
        if (s == 0) pix00 = b * HW + yi * IMW + xi;
    }

    // ---- pixel Jacobian rows ----
    const float* P2b = P2 + (size_t)b * 3 * HW;
    const float X = P2b[p], Y = P2b[HW + p], Z = P2b[2 * HW + p];
    const float fx = calibK[b * 9 + 0];
    const float fy = calibK[b * 9 + 4];
    const float fxZ = fx / Z, fyZ = fy / Z;
    const float fxXZ2 = fxZ * X / Z;
    const float fyYZ2 = fyZ * Y / Z;
    float r0[6] = { fxZ, 0.0f, -fxXZ2, -fxXZ2 * Y, fx + fxXZ2 * X, -fxZ * Y };
    float r1[6] = { 0.0f, fyZ, -fyYZ2, -fy - fyYZ2 * Y, fyYZ2 * X, fyZ * X };

    // ---- weights ----
    const float wP  = weight[(size_t)b * HW + p];
    const float swP = src_w[(size_t)b * HW + p];
    float wtw;
    {
        float wx = wxs[0], wy = wys[0];
        float v00 = tgt_w[pix00], v01 = tgt_w[pix00 + 1];
        float v10 = tgt_w[pix00 + IMW], v11 = tgt_w[pix00 + IMW + 1];
        wtw = v00 * (1.0f - wx) * (1.0f - wy) + v01 * wx * (1.0f - wy)
            + v10 * (1.0f - wx) * wy          + v11 * wx * wy;
    }
    const float w = swP * wtw * wP;

    // ---- channel-reduced moments ----
    float Sxx = 0.0f, Sxy = 0.0f, Syy = 0.0f, Tx = 0.0f, Ty = 0.0f;
    const float* srcb = src_feat + (size_t)b * CHN * HW + p;

#define SAMPLE(IDX, DEST) {                                              \
        const float* bp = tfT + off[IDX] + ch * 4;                       \
        float4 a4 = *(const float4*)(bp);                                \
        float4 b4 = *(const float4*)(bp + CHN);                          \
        float4 c4 = *(const float4*)(bp + IMW * CHN);                    \
        float4 d4 = *(const float4*)(bp + IMW * CHN + CHN);              \
        float wx = wxs[IDX], wy = wys[IDX];                              \
        float w00 = (1.0f - wx) * (1.0f - wy), w01 = wx * (1.0f - wy);   \
        float w10 = (1.0f - wx) * wy,          w11 = wx * wy;            \
        DEST.x = a4.x * w00 + b4.x * w01 + c4.x * w10 + d4.x * w11;      \
        DEST.y = a4.y * w00 + b4.y * w01 + c4.y * w10 + d4.y * w11;      \
        DEST.z = a4.z * w00 + b4.z * w01 + c4.z * w10 + d4.z * w11;      \
        DEST.w = a4.w * w00 + b4.w * w01 + c4.w * w10 + d4.w * w11;      \
    }

#define ACCUM(COMP, J) {                                                 \
        float sv  = srcb[(ch * 4 + J) * HW];                             \
        float res = sv - fs0.COMP;                                       \
        float gx  = (fs1.COMP - fs2.COMP) * 0.5f;                        \
        float gy  = (fs3.COMP - fs4.COMP) * 0.5f;                        \
        Sxx += gx * gx; Sxy += gx * gy; Syy += gy * gy;                  \
        Tx  += res * gx; Ty += res * gy;                                 \
    }

#pragma unroll
    for (int ch = 0; ch < 4; ++ch) {
        float4 fs0, fs1, fs2, fs3, fs4;
        SAMPLE(0, fs0) SAMPLE(1, fs1) SAMPLE(2, fs2) SAMPLE(3, fs3) SAMPLE(4, fs4)
        ACCUM(x, 0) ACCUM(y, 1) ACCUM(z, 2) ACCUM(w, 3)
    }
#undef SAMPLE
#undef ACCUM

    // ---- 27 per-point values, block tree-reduce ----
    const float Pm = w * Sxx, Qm = w * Sxy, Rm = w * Syy;
    const float tx = w * Tx,  ty = w * Ty;

    __shared__ float red[4][NPART];
    const int lane = threadIdx.x & 63, wv = threadIdx.x >> 6;

    int idx = 0;
#pragma unroll
    for (int k = 0; k < 6; ++k) {
#pragma unroll
        for (int l = 0; l < 6; ++l) {
            if (l < k) continue;
            float v = Pm * r0[k] * r0[l]
                    + Qm * (r0[k] * r1[l] + r1[k] * r0[l])
                    + Rm * r1[k] * r1[l];
            v += __shfl_down(v, 32); v += __shfl_down(v, 16);
            v += __shfl_down(v, 8);  v += __shfl_down(v, 4);
            v += __shfl_down(v, 2);  v += __shfl_down(v, 1);
            if (lane == 0) red[wv][idx] = v;
            ++idx;
        }
    }
#pragma unroll
    for (int k = 0; k < 6; ++k) {
        float v = tx * r0[k] + ty * r1[k];
        v += __shfl_down(v, 32); v += __shfl_down(v, 16);
        v += __shfl_down(v, 8);  v += __shfl_down(v, 4);
        v += __shfl_down(v, 2);  v += __shfl_down(v, 1);
        if (lane == 0) red[wv][21 + k] = v;
    }
    __syncthreads();
    if (threadIdx.x < NPART) {
        float s = red[0][threadIdx.x] + red[1][threadIdx.x]
                + red[2][threadIdx.x] + red[3][threadIdx.x];
        partials[((size_t)b * NBLK + blockIdx.x) * NPART + threadIdx.x] = s;
    }
}

// ---------------- kernel 2: double reduce + solve + se3_exp + compose ----------------
__global__ __launch_bounds__(64) void gn_solve(
    const float* __restrict__ partials,
    const float* __restrict__ poses,
    float* __restrict__ out)
{
    const int b = blockIdx.x;
    __shared__ double sums[NPART];
    const int t = threadIdx.x;
    if (t < NPART) {
        double s = 0.0;
        for (int j = 0; j < NBLK; ++j)
            s += (double)partials[((size_t)b * NBLK + j) * NPART + t];
        sums[t] = s;
    }
    __syncthreads();
    if (t != 0) return;

    double A[6][7];
    {
        int idx = 0;
        for (int k = 0; k < 6; ++k)
            for (int l = k; l < 6; ++l) {
                A[k][l] = sums[idx];
                A[l][k] = sums[idx];
                ++idx;
            }
        for (int k = 0; k < 6; ++k) A[k][6] = sums[21 + k];
    }
    // Gaussian elimination, partial pivoting
    for (int col = 0; col < 6; ++col) {
        int piv = col; double mx = fabs(A[col][col]);
        for (int rr = col + 1; rr < 6; ++rr) {
            double v = fabs(A[rr][col]);
            if (v > mx) { mx = v; piv = rr; }
        }
        if (piv != col)
            for (int j = col; j < 7; ++j) { double tmp = A[col][j]; A[col][j] = A[piv][j]; A[piv][j] = tmp; }
        double d = A[col][col];
        for (int rr = col + 1; rr < 6; ++rr) {
            double f = A[rr][col] / d;
            for (int j = col; j < 7; ++j) A[rr][j] -= f * A[col][j];
        }
    }
    double x[6];
    for (int i = 5; i >= 0; --i) {
        double s = A[i][6];
        for (int j = i + 1; j < 6; ++j) s -= A[i][j] * x[j];
        x[i] = s / A[i][i];
    }

    // se3_exp(x)
    const double rho[3] = { x[0], x[1], x[2] };
    const double phi[3] = { x[3], x[4], x[5] };
    const double th2 = phi[0]*phi[0] + phi[1]*phi[1] + phi[2]*phi[2];
    const bool small = th2 < 1e-8;
    const double th2s = small ? 1.0 : th2;
    const double th = sqrt(th2s);
    const double Ac = small ? 1.0 - th2 / 6.0   : sin(th) / th;
    const double Bc = small ? 0.5 - th2 / 24.0  : (1.0 - cos(th)) / th2s;
    const double Cc = small ? 1.0/6.0 - th2/120.0 : (th - sin(th)) / (th2s * th);
    const double Kh[3][3] = { { 0.0, -phi[2],  phi[1] },
                              {  phi[2], 0.0, -phi[0] },
                              { -phi[1],  phi[0], 0.0 } };
    double K2[3][3];
    for (int i = 0; i < 3; ++i)
        for (int j = 0; j < 3; ++j) {
            double s = 0.0;
            for (int k = 0; k < 3; ++k) s += Kh[i][k] * Kh[k][j];
            K2[i][j] = s;
        }
    double T[4][4];
    for (int i = 0; i < 3; ++i)
        for (int j = 0; j < 3; ++j) {
            double I = (i == j) ? 1.0 : 0.0;
            T[i][j] = I + Ac * Kh[i][j] + Bc * K2[i][j];
        }
    for (int i = 0; i < 3; ++i) {
        double s = 0.0;
        for (int j = 0; j < 3; ++j) {
            double I = (i == j) ? 1.0 : 0.0;
            double V = I + Bc * Kh[i][j] + Cc * K2[i][j];
            s += V * rho[j];
        }
        T[i][3] = s;
    }
    T[3][0] = 0.0; T[3][1] = 0.0; T[3][2] = 0.0; T[3][3] = 1.0;

    // new_pose = T @ pose
    const float* pz = poses + b * 16;
    for (int i = 0; i < 4; ++i)
        for (int j = 0; j < 4; ++j) {
            double s = 0.0;
            for (int k = 0; k < 4; ++k) s += T[i][k] * (double)pz[k * 4 + j];
            out[b * 16 + i * 4 + j] = (float)s;
        }
    for (int k = 0; k < 6; ++k)
        out[BATCH * 16 + b * 6 + k] = (float)x[k];
}

extern "C" void kernel_launch(void* const* d_in, const int* in_sizes, int n_in,
                              void* d_out, int out_size, void* d_ws, size_t ws_size,
                              hipStream_t stream) {
    const float* poses    = (const float*)d_in[0];
    const float* calibK   = (const float*)d_in[1];
    const float* p2       = (const float*)d_in[2];
    const float* P2       = (const float*)d_in[3];
    const float* weight   = (const float*)d_in[4];
    const float* src_feat = (const float*)d_in[5];
    const float* tgt_feat = (const float*)d_in[6];
    const float* src_w    = (const float*)d_in[7];
    const float* tgt_w    = (const float*)d_in[8];
    float* out = (float*)d_out;

    float* tfT      = (float*)d_ws;                          // B*HW*C floats
    float* partials = tfT + (size_t)BATCH * HW * CHN;        // B*NBLK*NPART floats

    hipLaunchKernelGGL(transpose_tgt, dim3(HW / 64, BATCH), dim3(256), 0, stream,
                       tgt_feat, tfT);
    hipLaunchKernelGGL(gn_accum, dim3(NBLK, BATCH), dim3(256), 0, stream,
                       p2, P2, calibK, weight, src_feat, src_w, tgt_w, tfT, partials);
    hipLaunchKernelGGL(gn_solve, dim3(BATCH), dim3(64), 0, stream,
                       partials, poses, out);
}

// Round 2
// 84.069 us; speedup vs baseline: 1.8324x; 1.8324x over previous
//
#include <hip/hip_runtime.h>
#include <hip/hip_fp16.h>
#include <math.h>

#define BATCH 16
#define CHN   16
#define IMH   96
#define IMW   320
#define HW    (IMH*IMW)          /* 30720 */
#define NBLK  (HW/256)           /* 120 blocks per batch */
#define NPART 27                 /* 21 (sym H) + 6 (b) */

typedef __attribute__((ext_vector_type(8))) _Float16 h8;

// ---------------- kernel 0: transpose+convert tgt_feat (B,C,H,W) fp32 -> (B,H,W,C) fp16 ----------------
__global__ __launch_bounds__(256) void transpose_tgt(const float* __restrict__ in,
                                                     _Float16* __restrict__ out) {
    const int b = blockIdx.y;
    const int p = blockIdx.x * 256 + threadIdx.x;
    const float* ip = in + (size_t)b * CHN * HW + p;
    h8 lo, hi;
#pragma unroll
    for (int k = 0; k < 8; ++k) {
        lo[k] = (_Float16)ip[k * HW];
        hi[k] = (_Float16)ip[(k + 8) * HW];
    }
    _Float16* op = out + ((size_t)b * HW + p) * CHN;
    *(h8*)(op)     = lo;
    *(h8*)(op + 8) = hi;
}

// ---------------- kernel 1: per-point moments + block-partial H/b ----------------
__global__ __launch_bounds__(256) void gn_accum(
    const float* __restrict__ p2,        // (B,2,5,1,H,W)
    const float* __restrict__ P2,        // (B,3,HW)
    const float* __restrict__ calibK,    // (B,3,3)
    const float* __restrict__ weight,    // (B,1,H,W)
    const float* __restrict__ src_feat,  // (B,C,H,W)
    const float* __restrict__ src_w,     // (B,1,H,W)
    const float* __restrict__ tgt_w,     // (B,1,H,W)
    const _Float16* __restrict__ tfT,    // (B,H,W,C) fp16 transposed tgt_feat
    float* __restrict__ partials)        // (B, NBLK, NPART)
{
    // XCD-aware decode: linear block n -> XCD n%8; b = n&15 puts batches {k,k+8}
    // on XCD k, so each XCD's L2 only ever holds 2 fp16 feature maps (2 MB).
    const int n   = blockIdx.x;
    const int b   = n & 15;
    const int blk = n >> 4;
    const int p   = blk * 256 + threadIdx.x;

    // ---- scrambled grid coords (faithful to transpose+reshape in reference) ----
    int   off[5];          // corner (y0,x0) base offset into tfT (halves)
    float wxs[5], wys[5];
    int   pix00 = 0;       // pixel offset for tgt_w bilinear (sample 0)
    const unsigned Gbase = ((unsigned)b * HW + (unsigned)p) * 5u;
#pragma unroll
    for (int s = 0; s < 5; ++s) {
        unsigned G    = Gbase + (unsigned)s;
        unsigned sBig = G / (unsigned)(BATCH * HW);
        unsigned r    = G - sBig * (unsigned)(BATCH * HW);
        unsigned bb   = r / (unsigned)HW;
        unsigned q    = r - bb * (unsigned)HW;
        const float* pb = p2 + (size_t)bb * (10 * HW) + (size_t)sBig * HW + q;
        float xp = pb[0];
        float yp = pb[5 * HW];
        // replicate reference normalization/unnormalization arithmetic
        float gx = 2.0f * (xp + 0.5f) / (float)IMW - 1.0f;
        float gy = 2.0f * (yp + 0.5f) / (float)IMH - 1.0f;
        float x  = (gx + 1.0f) * ((float)IMW * 0.5f) - 0.5f;
        float y  = (gy + 1.0f) * ((float)IMH * 0.5f) - 0.5f;
        float x0 = floorf(x), y0 = floorf(y);
        wxs[s] = x - x0;
        wys[s] = y - y0;
        int xi = (int)x0, yi = (int)y0;
        xi = min(max(xi, 0), IMW - 2);
        yi = min(max(yi, 0), IMH - 2);
        off[s] = ((b * IMH + yi) * IMW + xi) * CHN;
        if (s == 0) pix00 = b * HW + yi * IMW + xi;
    }

    // ---- pixel Jacobian rows ----
    const float* P2b = P2 + (size_t)b * 3 * HW;
    const float X = P2b[p], Y = P2b[HW + p], Z = P2b[2 * HW + p];
    const float fx = calibK[b * 9 + 0];
    const float fy = calibK[b * 9 + 4];
    const float fxZ = fx / Z, fyZ = fy / Z;
    const float fxXZ2 = fxZ * X / Z;
    const float fyYZ2 = fyZ * Y / Z;
    float r0[6] = { fxZ, 0.0f, -fxXZ2, -fxXZ2 * Y, fx + fxXZ2 * X, -fxZ * Y };
    float r1[6] = { 0.0f, fyZ, -fyYZ2, -fy - fyYZ2 * Y, fyYZ2 * X, fyZ * X };

    // ---- weights ----
    const float wP  = weight[(size_t)b * HW + p];
    const float swP = src_w[(size_t)b * HW + p];
    float wtw;
    {
        float wx = wxs[0], wy = wys[0];
        float v00 = tgt_w[pix00], v01 = tgt_w[pix00 + 1];
        float v10 = tgt_w[pix00 + IMW], v11 = tgt_w[pix00 + IMW + 1];
        wtw = v00 * (1.0f - wx) * (1.0f - wy) + v01 * wx * (1.0f - wy)
            + v10 * (1.0f - wx) * wy          + v11 * wx * wy;
    }
    const float w = swP * wtw * wP;

    // ---- channel-reduced moments, two 8-channel passes ----
    float Sxx = 0.0f, Sxy = 0.0f, Syy = 0.0f, Tx = 0.0f, Ty = 0.0f;
    const float* srcb = src_feat + (size_t)b * CHN * HW + p;

#pragma unroll
    for (int pass = 0; pass < 2; ++pass) {
        // load all 20 corner vectors of this pass up-front (independent addrs)
        h8 ca[5], cb[5], cc[5], cd[5];
#pragma unroll
        for (int s = 0; s < 5; ++s) {
            const _Float16* bp = tfT + off[s] + pass * 8;
            ca[s] = *(const h8*)(bp);
            cb[s] = *(const h8*)(bp + CHN);
            cc[s] = *(const h8*)(bp + IMW * CHN);
            cd[s] = *(const h8*)(bp + IMW * CHN + CHN);
        }
        float fs[5][8];
#pragma unroll
        for (int s = 0; s < 5; ++s) {
            float wx = wxs[s], wy = wys[s];
            float w00 = (1.0f - wx) * (1.0f - wy), w01 = wx * (1.0f - wy);
            float w10 = (1.0f - wx) * wy,          w11 = wx * wy;
#pragma unroll
            for (int j = 0; j < 8; ++j) {
                fs[s][j] = (float)ca[s][j] * w00 + (float)cb[s][j] * w01
                         + (float)cc[s][j] * w10 + (float)cd[s][j] * w11;
            }
        }
#pragma unroll
        for (int j = 0; j < 8; ++j) {
            float sv  = srcb[(pass * 8 + j) * HW];
            float res = sv - fs[0][j];
            float gx  = (fs[1][j] - fs[2][j]) * 0.5f;
            float gy  = (fs[3][j] - fs[4][j]) * 0.5f;
            Sxx += gx * gx; Sxy += gx * gy; Syy += gy * gy;
            Tx  += res * gx; Ty  += res * gy;
        }
    }

    // ---- 27 per-point values, block tree-reduce ----
    const float Pm = w * Sxx, Qm = w * Sxy, Rm = w * Syy;
    const float tx = w * Tx,  ty = w * Ty;

    __shared__ float red[4][NPART];
    const int lane = threadIdx.x & 63, wv = threadIdx.x >> 6;

    int idx = 0;
#pragma unroll
    for (int k = 0; k < 6; ++k) {
#pragma unroll
        for (int l = 0; l < 6; ++l) {
            if (l < k) continue;
            float v = Pm * r0[k] * r0[l]
                    + Qm * (r0[k] * r1[l] + r1[k] * r0[l])
                    + Rm * r1[k] * r1[l];
            v += __shfl_down(v, 32); v += __shfl_down(v, 16);
            v += __shfl_down(v, 8);  v += __shfl_down(v, 4);
            v += __shfl_down(v, 2);  v += __shfl_down(v, 1);
            if (lane == 0) red[wv][idx] = v;
            ++idx;
        }
    }
#pragma unroll
    for (int k = 0; k < 6; ++k) {
        float v = tx * r0[k] + ty * r1[k];
        v += __shfl_down(v, 32); v += __shfl_down(v, 16);
        v += __shfl_down(v, 8);  v += __shfl_down(v, 4);
        v += __shfl_down(v, 2);  v += __shfl_down(v, 1);
        if (lane == 0) red[wv][21 + k] = v;
    }
    __syncthreads();
    if (threadIdx.x < NPART) {
        float s = red[0][threadIdx.x] + red[1][threadIdx.x]
                + red[2][threadIdx.x] + red[3][threadIdx.x];
        partials[((size_t)b * NBLK + blk) * NPART + threadIdx.x] = s;
    }
}

// ---------------- kernel 2: double reduce + solve + se3_exp + compose ----------------
__global__ __launch_bounds__(64) void gn_solve(
    const float* __restrict__ partials,
    const float* __restrict__ poses,
    float* __restrict__ out)
{
    const int b = blockIdx.x;
    __shared__ double sums[NPART];
    const int t = threadIdx.x;
    if (t < NPART) {
        double s = 0.0;
        for (int j = 0; j < NBLK; ++j)
            s += (double)partials[((size_t)b * NBLK + j) * NPART + t];
        sums[t] = s;
    }
    __syncthreads();
    if (t != 0) return;

    double A[6][7];
    {
        int idx = 0;
        for (int k = 0; k < 6; ++k)
            for (int l = k; l < 6; ++l) {
                A[k][l] = sums[idx];
                A[l][k] = sums[idx];
                ++idx;
            }
        for (int k = 0; k < 6; ++k) A[k][6] = sums[21 + k];
    }
    // Gaussian elimination, partial pivoting
    for (int col = 0; col < 6; ++col) {
        int piv = col; double mx = fabs(A[col][col]);
        for (int rr = col + 1; rr < 6; ++rr) {
            double v = fabs(A[rr][col]);
            if (v > mx) { mx = v; piv = rr; }
        }
        if (piv != col)
            for (int j = col; j < 7; ++j) { double tmp = A[col][j]; A[col][j] = A[piv][j]; A[piv][j] = tmp; }
        double d = A[col][col];
        for (int rr = col + 1; rr < 6; ++rr) {
            double f = A[rr][col] / d;
            for (int j = col; j < 7; ++j) A[rr][j] -= f * A[col][j];
        }
    }
    double x[6];
    for (int i = 5; i >= 0; --i) {
        double s = A[i][6];
        for (int j = i + 1; j < 6; ++j) s -= A[i][j] * x[j];
        x[i] = s / A[i][i];
    }

    // se3_exp(x)
    const double rho[3] = { x[0], x[1], x[2] };
    const double phi[3] = { x[3], x[4], x[5] };
    const double th2 = phi[0]*phi[0] + phi[1]*phi[1] + phi[2]*phi[2];
    const bool small = th2 < 1e-8;
    const double th2s = small ? 1.0 : th2;
    const double th = sqrt(th2s);
    const double Ac = small ? 1.0 - th2 / 6.0   : sin(th) / th;
    const double Bc = small ? 0.5 - th2 / 24.0  : (1.0 - cos(th)) / th2s;
    const double Cc = small ? 1.0/6.0 - th2/120.0 : (th - sin(th)) / (th2s * th);
    const double Kh[3][3] = { { 0.0, -phi[2],  phi[1] },
                              {  phi[2], 0.0, -phi[0] },
                              { -phi[1],  phi[0], 0.0 } };
    double K2[3][3];
    for (int i = 0; i < 3; ++i)
        for (int j = 0; j < 3; ++j) {
            double s = 0.0;
            for (int k = 0; k < 3; ++k) s += Kh[i][k] * Kh[k][j];
            K2[i][j] = s;
        }
    double T[4][4];
    for (int i = 0; i < 3; ++i)
        for (int j = 0; j < 3; ++j) {
            double I = (i == j) ? 1.0 : 0.0;
            T[i][j] = I + Ac * Kh[i][j] + Bc * K2[i][j];
        }
    for (int i = 0; i < 3; ++i) {
        double s = 0.0;
        for (int j = 0; j < 3; ++j) {
            double I = (i == j) ? 1.0 : 0.0;
            double V = I + Bc * Kh[i][j] + Cc * K2[i][j];
            s += V * rho[j];
        }
        T[i][3] = s;
    }
    T[3][0] = 0.0; T[3][1] = 0.0; T[3][2] = 0.0; T[3][3] = 1.0;

    // new_pose = T @ pose
    const float* pz = poses + b * 16;
    for (int i = 0; i < 4; ++i)
        for (int j = 0; j < 4; ++j) {
            double s = 0.0;
            for (int k = 0; k < 4; ++k) s += T[i][k] * (double)pz[k * 4 + j];
            out[b * 16 + i * 4 + j] = (float)s;
        }
    for (int k = 0; k < 6; ++k)
        out[BATCH * 16 + b * 6 + k] = (float)x[k];
}

extern "C" void kernel_launch(void* const* d_in, const int* in_sizes, int n_in,
                              void* d_out, int out_size, void* d_ws, size_t ws_size,
                              hipStream_t stream) {
    const float* poses    = (const float*)d_in[0];
    const float* calibK   = (const float*)d_in[1];
    const float* p2       = (const float*)d_in[2];
    const float* P2       = (const float*)d_in[3];
    const float* weight   = (const float*)d_in[4];
    const float* src_feat = (const float*)d_in[5];
    const float* tgt_feat = (const float*)d_in[6];
    const float* src_w    = (const float*)d_in[7];
    const float* tgt_w    = (const float*)d_in[8];
    float* out = (float*)d_out;

    _Float16* tfT   = (_Float16*)d_ws;                        // B*HW*C halves
    float* partials = (float*)(tfT + (size_t)BATCH * HW * CHN); // B*NBLK*NPART floats

    hipLaunchKernelGGL(transpose_tgt, dim3(HW / 256, BATCH), dim3(256), 0, stream,
                       tgt_feat, tfT);
    hipLaunchKernelGGL(gn_accum, dim3(NBLK * BATCH), dim3(256), 0, stream,
                       p2, P2, calibK, weight, src_feat, src_w, tgt_w, tfT, partials);
    hipLaunchKernelGGL(gn_solve, dim3(BATCH), dim3(64), 0, stream,
                       partials, poses, out);
}